// Round 5
// baseline (1351.047 us; speedup 1.0000x reference)
//
#include <hip/hip_runtime.h>

#define NE 128
#define NI 32
#define NT 160   // NE + NI
#define NC 10
#define BB 512
#define LL 64
#define DD 784
#define MM (BB*LL)

// ws layout (float offsets)
#define G_OFF   0
#define G_SZ    (NT*NT)              // 25600
#define WT4_OFF (G_OFF + G_SZ)
#define WT4_SZ  (DD*NT)              // 125440, layout [k4][j][4]
#define U_OFF   (WT4_OFF + WT4_SZ)   // 151040
#define U_SZ    (MM*NT)              // 5242880

// out layout (float offsets)
#define O_LOGITS 0
#define O_LAST   327680
#define O_RE     332800
#define O_RI     4527104
#define O_BALE   5575680
#define O_BALI   9769984

// LDS-only barrier (recur): publish ds_writes without draining vmcnt.
#define LDS_BARRIER() asm volatile("s_waitcnt lgkmcnt(0)\n\ts_barrier" ::: "memory")

// 16B global->LDS direct copy (no VGPR round-trip). LDS dest is wave-uniform
// base + lane*16, so the lds pointer must be the wave's base slot.
#define GLOBAL_LOAD_LDS16(gp, lp)                                              \
  __builtin_amdgcn_global_load_lds(                                            \
      (const __attribute__((address_space(1))) void*)(gp),                     \
      (__attribute__((address_space(3))) void*)(lp), 16, 0, 0)

// ---------------------------------------------------------------------------
// Prep: Dale-rectified recurrent matrix G[k][j] and input weights pre-
// transposed to WT4[k4][j][kk] (so GEMM staging is a contiguous float4 copy).
// ---------------------------------------------------------------------------
__global__ void prep_kernel(const float* __restrict__ Wxe, const float* __restrict__ Wxi,
                            const float* __restrict__ Wee, const float* __restrict__ Wie,
                            const float* __restrict__ Wei, const float* __restrict__ Wii,
                            float* __restrict__ ws) {
  int idx = blockIdx.x * blockDim.x + threadIdx.x;
  const int total = G_SZ + WT4_SZ;
  if (idx >= total) return;
  if (idx < G_SZ) {
    int k = idx / NT, j = idx % NT;
    float g;
    if (j < NE) {
      if (k < NE) g =  fmaxf(Wee[j*NE + k], 0.f);
      else        g = -fmaxf(Wie[j*NI + (k-NE)], 0.f);
    } else {
      int ji = j - NE;
      if (k < NE) g =  fmaxf(Wei[ji*NE + k], 0.f);
      else        g = -fmaxf(Wii[ji*NI + (k-NE)], 0.f);
    }
    ws[G_OFF + k*NT + j] = g;
  } else {
    int t = idx - G_SZ;
    int d = t / NT, j = t % NT;
    float v = (j < NE) ? fmaxf(Wxe[j*DD + d], 0.f)
                       : fmaxf(Wxi[(j-NE)*DD + d], 0.f);
    ws[WT4_OFF + ((size_t)(d >> 2) * NT + j) * 4 + (d & 3)] = v;
  }
}

// ---------------------------------------------------------------------------
// GEMM v4: U[m][j] = X[m][:] @ Wx^T. 256 blocks (1/CU), m-tile 128, full K in
// 28 tiles of 28. X staged via global_load_lds (zero staging VGPRs) into a
// linear [k4][row] float4 layout; bank conflicts avoided by ROTATED read
// order rot=(e+2*ty)&7 (4 ty-groups/wave hit disjoint bank quads; acc index
// stays static — row ASSIGNMENT is permuted instead). W staged global->reg->
// LDS at loop top (wr live only briefly) into stride-11-padded layout
// (2-way conflicts = free). No prefetch regs live across compute -> no spill.
// ---------------------------------------------------------------------------
__global__ __launch_bounds__(256, 1) void gemm_kernel(const float* __restrict__ X,
                                                      const float* __restrict__ ws,
                                                      float* __restrict__ U) {
  __shared__ float xs[2][896 * 4];      // [buf][k4*128+row] float4 linear, 2x14 KB
  __shared__ float wt[2][7 * 176 * 4];  // [buf][k4][tx*11+c] float4, 2x19.7 KB
  const int tid = threadIdx.x;
  const int tx = tid & 15, ty = tid >> 4;   // ty 0..15, 8 rows each
  const int m0 = blockIdx.x * 128;
  const float4* WT4 = (const float4*)(ws + WT4_OFF);
  const int ty3 = (ty & 3) * 2;             // read-rotation seed

  float acc[8][10];
  #pragma unroll
  for (int i = 0; i < 8; ++i)
    #pragma unroll
    for (int c = 0; c < 10; ++c) acc[i][c] = 0.f;

  // ---- prologue: stage tile 0 into buffer 0 ----
  {
    float4 wr[5];
    #pragma unroll
    for (int n = 0; n < 5; ++n) {
      int f = tid + n * 256;
      if (f < 1120) wr[n] = WT4[f];
    }
    #pragma unroll
    for (int n = 0; n < 4; ++n) {
      int i = tid + n * 256;
      if (i < 896) {
        int k4 = i >> 7, r = i & 127;
        const float* gp = X + (size_t)(m0 + r) * DD + k4 * 4;
        float* lp = xs[0] + ((i & ~63) << 2);
        GLOBAL_LOAD_LDS16(gp, lp);
      }
    }
    #pragma unroll
    for (int n = 0; n < 5; ++n) {
      int f = tid + n * 256;
      if (f < 1120) {
        int k4r = f / 160, j = f - k4r * 160;
        int tx2 = j / 10, c2 = j - tx2 * 10;
        ((float4*)wt[0])[k4r * 176 + tx2 * 11 + c2] = wr[n];
      }
    }
    __syncthreads();
  }

  for (int t = 0; t < 28; ++t) {
    const int cur = t & 1, nb = 1 - cur;
    // ---- stage tile t+1 into back buffer (W: reg bounce; X: lds-direct) ----
    if (t < 27) {
      const int k0f = (t + 1) * 28;
      float4 wr[5];
      #pragma unroll
      for (int n = 0; n < 5; ++n) {
        int f = tid + n * 256;
        if (f < 1120) wr[n] = WT4[(size_t)(t + 1) * 1120 + f];
      }
      #pragma unroll
      for (int n = 0; n < 4; ++n) {
        int i = tid + n * 256;
        if (i < 896) {
          int k4 = i >> 7, r = i & 127;
          const float* gp = X + (size_t)(m0 + r) * DD + k0f + k4 * 4;
          float* lp = xs[nb] + ((i & ~63) << 2);
          GLOBAL_LOAD_LDS16(gp, lp);
        }
      }
      #pragma unroll
      for (int n = 0; n < 5; ++n) {
        int f = tid + n * 256;
        if (f < 1120) {
          int k4r = f / 160, j = f - k4r * 160;
          int tx2 = j / 10, c2 = j - tx2 * 10;
          ((float4*)wt[nb])[k4r * 176 + tx2 * 11 + c2] = wr[n];
        }
      }
    }
    // ---- compute on buffer cur ----
    const float* xsc = xs[cur];
    const float4* wp = (const float4*)wt[cur];
    #pragma unroll
    for (int kk4 = 0; kk4 < 7; ++kk4) {
      float4 wv[10];
      #pragma unroll
      for (int c = 0; c < 10; ++c)
        wv[c] = wp[kk4 * 176 + tx * 11 + c];
      float4 xv[8];
      #pragma unroll
      for (int e = 0; e < 8; ++e) {
        int rot = (e + ty3) & 7;
        xv[e] = *(const float4*)(xsc + ((kk4 * 128 + ty * 8 + rot) << 2));
      }
      #pragma unroll
      for (int e = 0; e < 8; ++e)
        #pragma unroll
        for (int c = 0; c < 10; ++c)
          acc[e][c] += xv[e].x * wv[c].x + xv[e].y * wv[c].y
                     + xv[e].z * wv[c].z + xv[e].w * wv[c].w;
    }
    __syncthreads();
  }

  // ---- epilogue: acc[e] holds row ty*8 + rot(e) ----
  #pragma unroll
  for (int e = 0; e < 8; ++e) {
    const int row = ty * 8 + ((e + ty3) & 7);
    float* base = U + (size_t)(m0 + row) * NT + tx * 10;
    #pragma unroll
    for (int c2 = 0; c2 < 5; ++c2) {
      float2 v = make_float2(acc[e][c2 * 2], acc[e][c2 * 2 + 1]);
      *(float2*)(base + c2 * 2) = v;
    }
  }
}

// ---------------------------------------------------------------------------
// Recurrent scan v3 (unchanged). 512 blocks x 256 threads, one batch row per
// block, G in registers, one LDS-only barrier per step, U prefetch 1 ahead.
// ---------------------------------------------------------------------------
__global__ __launch_bounds__(256, 2) void recur_kernel(
    const float* __restrict__ ws,
    const float* __restrict__ be, const float* __restrict__ bi,
    float* __restrict__ out) {
  __shared__ float rbuf[2][NT];       // [parity][j]
  __shared__ float balbuf[2][NT];
  __shared__ float biasL[NT];

  const int tid  = threadIdx.x;
  const int lane = tid & 63;
  const int wave = tid >> 6;
  const int jc   = (wave << 3) | (lane & 7);  // 0..31
  const int kc   = (lane >> 3) & 7;           // 0..7
  const int j0   = jc * 5;
  const int k0   = kc * 20;
  const int b    = blockIdx.x;

  const float* G = ws + G_OFF;
  const float* U = ws + U_OFF;

  float g[20][5];
  #pragma unroll
  for (int kk = 0; kk < 20; ++kk)
    #pragma unroll
    for (int c = 0; c < 5; ++c)
      g[kk][c] = G[(size_t)(k0 + kk) * NT + j0 + c];

  if (tid < NT) biasL[tid] = (tid < NE) ? be[tid] : bi[tid - NE];
  for (int i = tid; i < 2 * NT; i += 256) (&rbuf[0][0])[i] = 0.f;

  const bool owner = (kc == 0);
  float u[5];
  if (owner) {
    const size_t ub = ((size_t)b * LL) * NT + j0;
    #pragma unroll
    for (int c = 0; c < 5; ++c) u[c] = U[ub + c];
  }
  float s[5];
  #pragma unroll
  for (int c = 0; c < 5; ++c) s[c] = 0.f;

  __syncthreads();

  for (int l = 0; l < LL; ++l) {
    const int p = l & 1;
    // ---- store step l-1 outputs (no barrier depends on these) ----
    if (l > 0) {
      const size_t ob = (size_t)b * LL + (l - 1);
      if (tid < NE) {
        out[O_RE   + ob * NE + tid] = rbuf[p][tid];
        out[O_BALE + ob * NE + tid] = balbuf[p][tid];
      } else if (tid < NT) {
        const int j2 = tid - NE;
        out[O_RI   + ob * NI + j2] = rbuf[p][NE + j2];
        out[O_BALI + ob * NI + j2] = balbuf[p][NE + j2];
      }
    }
    // ---- prefetch next step's U (owners) ----
    float nu[5];
    if (owner && l + 1 < LL) {
      const size_t nb = ((size_t)b * LL + (l + 1)) * NT + j0;
      #pragma unroll
      for (int c = 0; c < 5; ++c) nu[c] = U[nb + c];
    }
    // ---- partial dots over this thread's k-chunk ----
    float a[5];
    #pragma unroll
    for (int c = 0; c < 5; ++c) a[c] = 0.f;
    #pragma unroll
    for (int kk4 = 0; kk4 < 5; ++kk4) {
      float4 rv = *(const float4*)(&rbuf[p][k0 + kk4 * 4]);
      #pragma unroll
      for (int c = 0; c < 5; ++c)
        a[c] += rv.x * g[kk4*4+0][c] + rv.y * g[kk4*4+1][c]
              + rv.z * g[kk4*4+2][c] + rv.w * g[kk4*4+3][c];
    }
    // ---- butterfly reduce over kc (lane bits 3..5) ----
    #pragma unroll
    for (int c = 0; c < 5; ++c) {
      float v = a[c];
      v += __shfl_xor(v, 8, 64);
      v += __shfl_xor(v, 16, 64);
      v += __shfl_xor(v, 32, 64);
      a[c] = v;
    }
    // ---- owner lanes update state, write next-parity buffers ----
    if (owner) {
      #pragma unroll
      for (int c = 0; c < 5; ++c) {
        float bal = a[c] + u[c];
        balbuf[1 - p][j0 + c] = bal;
        float sn = 0.5f * (s[c] + bal + biasL[j0 + c]);
        s[c] = sn;
        rbuf[1 - p][j0 + c] = fmaxf(sn, 0.f);
      }
      #pragma unroll
      for (int c = 0; c < 5; ++c) u[c] = nu[c];
    }
    LDS_BARRIER();
  }
  // ---- final store: step 63 outputs live in parity-0 buffers ----
  {
    const size_t ob = (size_t)b * LL + 63;
    if (tid < NE) {
      out[O_RE   + ob * NE + tid] = rbuf[0][tid];
      out[O_BALE + ob * NE + tid] = balbuf[0][tid];
    } else if (tid < NT) {
      const int j2 = tid - NE;
      out[O_RI   + ob * NI + j2] = rbuf[0][NE + j2];
      out[O_BALI + ob * NI + j2] = balbuf[0][NE + j2];
    }
  }
}

// ---------------------------------------------------------------------------
// Logits: [32768 x 128] @ Wro^T + bro. One thread per (m, class).
// ---------------------------------------------------------------------------
__global__ __launch_bounds__(256) void logits_kernel(const float* __restrict__ Wro,
                                                     const float* __restrict__ bro,
                                                     float* __restrict__ out) {
  __shared__ float WroL[NC * 132];   // row-stride 132 breaks bank alignment
  __shared__ float broL[NC];
  const int tid = threadIdx.x;
  for (int i = tid; i < NC * NE; i += 256) {
    int c = i >> 7, k = i & 127;
    WroL[c * 132 + k] = Wro[i];
  }
  if (tid < NC) broL[tid] = bro[tid];
  __syncthreads();
  const int idx = blockIdx.x * 256 + tid;   // 0..327679 exact
  const int m = idx / 10, c = idx - m * 10;
  const float* re = out + O_RE + (size_t)m * NE;
  float v = broL[c];
  #pragma unroll
  for (int t4 = 0; t4 < 32; ++t4) {
    float4 rv = *(const float4*)(re + t4 * 4);
    float4 wv = *(const float4*)(&WroL[c * 132 + t4 * 4]);
    v += rv.x * wv.x + rv.y * wv.y + rv.z * wv.z + rv.w * wv.w;
  }
  out[O_LOGITS + (size_t)m * NC + c] = v;
  if ((m & 63) == 63) out[O_LAST + (size_t)(m >> 6) * NC + c] = v;
}

extern "C" void kernel_launch(void* const* d_in, const int* in_sizes, int n_in,
                              void* d_out, int out_size, void* d_ws, size_t ws_size,
                              hipStream_t stream) {
  const float* x   = (const float*)d_in[0];
  const float* Wxe = (const float*)d_in[1];
  const float* Wxi = (const float*)d_in[2];
  const float* Wee = (const float*)d_in[3];
  const float* Wie = (const float*)d_in[4];
  const float* Wei = (const float*)d_in[5];
  const float* Wii = (const float*)d_in[6];
  const float* be  = (const float*)d_in[7];
  const float* bi  = (const float*)d_in[8];
  const float* Wro = (const float*)d_in[9];
  const float* bro = (const float*)d_in[10];
  float* ws  = (float*)d_ws;
  float* out = (float*)d_out;

  hipLaunchKernelGGL(prep_kernel, dim3((G_SZ + WT4_SZ + 255)/256), dim3(256), 0, stream,
                     Wxe, Wxi, Wee, Wie, Wei, Wii, ws);
  hipLaunchKernelGGL(gemm_kernel, dim3(MM/128), dim3(256), 0, stream,
                     x, ws, ws + U_OFF);
  hipLaunchKernelGGL(recur_kernel, dim3(BB), dim3(256), 0, stream,
                     ws, be, bi, out);
  hipLaunchKernelGGL(logits_kernel, dim3(MM * NC / 256), dim3(256), 0, stream,
                     Wro, bro, out);
}

// Round 6
// 313.908 us; speedup vs baseline: 4.3040x; 4.3040x over previous
//
#include <hip/hip_runtime.h>

#define NE 128
#define NI 32
#define NT 160   // NE + NI
#define NC 10
#define BB 512
#define LL 64
#define DD 784
#define KP 800   // K padded to 25*32 for MFMA
#define MM (BB*LL)

// ws layout (float offsets)
#define G_OFF   0
#define G_SZ    (NT*NT)              // 25600
#define WH_OFF  (G_OFF + G_SZ)       // bf16 plane Wh[n][KP], 128000 ushort = 64000 floats
#define WL_OFF  (WH_OFF + 64000)     // bf16 plane Wl[n][KP]
#define U_OFF   (WL_OFF + 64000)     // 153600
#define U_SZ    (MM*NT)              // 5242880

// out layout (float offsets)
#define O_LOGITS 0
#define O_LAST   327680
#define O_RE     332800
#define O_RI     4527104
#define O_BALE   5575680
#define O_BALI   9769984

// LDS-only barrier (recur): publish ds_writes without draining vmcnt.
#define LDS_BARRIER() asm volatile("s_waitcnt lgkmcnt(0)\n\ts_barrier" ::: "memory")

typedef __attribute__((ext_vector_type(8))) short short8;
typedef __attribute__((ext_vector_type(4))) float af4;

static __device__ __forceinline__ unsigned short f2bf(float f) {   // RNE, finite inputs
  unsigned u = __float_as_uint(f);
  return (unsigned short)((u + 0x7FFFu + ((u >> 16) & 1u)) >> 16);
}
static __device__ __forceinline__ float bf2f(unsigned short h) {
  return __uint_as_float((unsigned)h << 16);
}

// ---------------------------------------------------------------------------
// Prep: Dale-rectified recurrent matrix G[k][j] (fp32) + input weights as
// split-bf16 planes Wh/Wl[n][KP] (k-padded with zeros), n-major so a B-frag
// (8 consecutive k of one n) is one 16B load.
// ---------------------------------------------------------------------------
__global__ void prep_kernel(const float* __restrict__ Wxe, const float* __restrict__ Wxi,
                            const float* __restrict__ Wee, const float* __restrict__ Wie,
                            const float* __restrict__ Wei, const float* __restrict__ Wii,
                            float* __restrict__ ws) {
  int idx = blockIdx.x * blockDim.x + threadIdx.x;
  const int total = G_SZ + NT * KP;
  if (idx >= total) return;
  if (idx < G_SZ) {
    int k = idx / NT, j = idx % NT;
    float g;
    if (j < NE) {
      if (k < NE) g =  fmaxf(Wee[j*NE + k], 0.f);
      else        g = -fmaxf(Wie[j*NI + (k-NE)], 0.f);
    } else {
      int ji = j - NE;
      if (k < NE) g =  fmaxf(Wei[ji*NE + k], 0.f);
      else        g = -fmaxf(Wii[ji*NI + (k-NE)], 0.f);
    }
    ws[G_OFF + k*NT + j] = g;
  } else {
    int t = idx - G_SZ;
    int n = t / KP, k = t - n * KP;
    float v = 0.f;
    if (k < DD)
      v = (n < NE) ? fmaxf(Wxe[n*DD + k], 0.f) : fmaxf(Wxi[(n-NE)*DD + k], 0.f);
    unsigned short h = f2bf(v);
    unsigned short l = f2bf(v - bf2f(h));
    ((unsigned short*)(ws + WH_OFF))[t] = h;
    ((unsigned short*)(ws + WL_OFF))[t] = l;
  }
}

// ---------------------------------------------------------------------------
// GEMM v5 (MFMA): U[m][n] = X[m][:] @ W^T via split-bf16, 3 passes:
// xh*wh + xh*wl + xl*wh (residual ~2^-16 rel — well under fp32's margin).
// 256 blocks x 4 waves; wave owns 32 rows (2 m-subtiles) x 160 cols
// (10 n-tiles) of 16x16x32 MFMAs. NO LDS: A-frags load fp32 straight from X
// (4 quads of one row = contiguous 64B) and convert in-reg; B-frags load from
// L2-resident Wh/Wl planes. Frag layouts per m89/m120: A[m=lane&15][k=quad*8+j],
// B[n=lane&15][k=quad*8+j], D row=quad*4+reg, col=lane&15.
// ---------------------------------------------------------------------------
__global__ __launch_bounds__(256, 1) void gemm_kernel(const float* __restrict__ X,
                                                      const float* __restrict__ ws,
                                                      float* __restrict__ U) {
  const int tid  = threadIdx.x;
  const int lane = tid & 63;
  const int wave = tid >> 6;
  const int n16  = lane & 15;
  const int quad = lane >> 4;
  const int mbase = blockIdx.x * 128 + wave * 32;

  const unsigned short* Wh = (const unsigned short*)(ws + WH_OFF);
  const unsigned short* Wl = (const unsigned short*)(ws + WL_OFF);

  af4 acc[2][10];
  #pragma unroll
  for (int ms = 0; ms < 2; ++ms)
    #pragma unroll
    for (int nt = 0; nt < 10; ++nt)
      #pragma unroll
      for (int r = 0; r < 4; ++r) acc[ms][nt][r] = 0.f;

  const float* xrow[2] = { X + (size_t)(mbase + n16) * DD,
                           X + (size_t)(mbase + 16 + n16) * DD };

  // ---- main K loop: 24 full steps (k < 768 + 32, all in-bounds) ----
  for (int ks = 0; ks < 24; ++ks) {
    const int kb = ks * 32 + quad * 8;
    short8 ah[2], al[2];
    #pragma unroll
    for (int ms = 0; ms < 2; ++ms) {
      float4 v0 = *(const float4*)(xrow[ms] + kb);
      float4 v1 = *(const float4*)(xrow[ms] + kb + 4);
      float f[8] = {v0.x, v0.y, v0.z, v0.w, v1.x, v1.y, v1.z, v1.w};
      #pragma unroll
      for (int j = 0; j < 8; ++j) {
        unsigned short h = f2bf(f[j]);
        ah[ms][j] = (short)h;
        al[ms][j] = (short)f2bf(f[j] - bf2f(h));
      }
    }
    short8 bh[10], bl[10];
    #pragma unroll
    for (int nt = 0; nt < 10; ++nt) {
      const size_t off = (size_t)(nt * 16 + n16) * KP + kb;
      bh[nt] = *(const short8*)(Wh + off);
      bl[nt] = *(const short8*)(Wl + off);
    }
    #pragma unroll
    for (int ms = 0; ms < 2; ++ms)
      #pragma unroll
      for (int nt = 0; nt < 10; ++nt) {
        acc[ms][nt] = __builtin_amdgcn_mfma_f32_16x16x32_bf16(ah[ms], bh[nt], acc[ms][nt], 0, 0, 0);
        acc[ms][nt] = __builtin_amdgcn_mfma_f32_16x16x32_bf16(ah[ms], bl[nt], acc[ms][nt], 0, 0, 0);
        acc[ms][nt] = __builtin_amdgcn_mfma_f32_16x16x32_bf16(al[ms], bh[nt], acc[ms][nt], 0, 0, 0);
      }
  }

  // ---- peeled tail step ks=24: k = 768 + quad*8; quads 2,3 are past DD ----
  {
    const int kb = 768 + quad * 8;
    const bool ok = kb < DD;
    short8 ah[2], al[2];
    #pragma unroll
    for (int ms = 0; ms < 2; ++ms) {
      float f[8] = {0,0,0,0,0,0,0,0};
      if (ok) {
        float4 v0 = *(const float4*)(xrow[ms] + kb);
        float4 v1 = *(const float4*)(xrow[ms] + kb + 4);
        f[0]=v0.x; f[1]=v0.y; f[2]=v0.z; f[3]=v0.w;
        f[4]=v1.x; f[5]=v1.y; f[6]=v1.z; f[7]=v1.w;
      }
      #pragma unroll
      for (int j = 0; j < 8; ++j) {
        unsigned short h = f2bf(f[j]);
        ah[ms][j] = (short)h;
        al[ms][j] = (short)f2bf(f[j] - bf2f(h));
      }
    }
    short8 bh[10], bl[10];
    #pragma unroll
    for (int nt = 0; nt < 10; ++nt) {
      const size_t off = (size_t)(nt * 16 + n16) * KP + kb;
      bh[nt] = *(const short8*)(Wh + off);   // zero-padded region, always safe
      bl[nt] = *(const short8*)(Wl + off);
    }
    #pragma unroll
    for (int ms = 0; ms < 2; ++ms)
      #pragma unroll
      for (int nt = 0; nt < 10; ++nt) {
        acc[ms][nt] = __builtin_amdgcn_mfma_f32_16x16x32_bf16(ah[ms], bh[nt], acc[ms][nt], 0, 0, 0);
        acc[ms][nt] = __builtin_amdgcn_mfma_f32_16x16x32_bf16(ah[ms], bl[nt], acc[ms][nt], 0, 0, 0);
        acc[ms][nt] = __builtin_amdgcn_mfma_f32_16x16x32_bf16(al[ms], bh[nt], acc[ms][nt], 0, 0, 0);
      }
  }

  // ---- epilogue: D row = quad*4 + reg, col = n16 ----
  #pragma unroll
  for (int ms = 0; ms < 2; ++ms)
    #pragma unroll
    for (int nt = 0; nt < 10; ++nt)
      #pragma unroll
      for (int r = 0; r < 4; ++r) {
        const int row = mbase + ms * 16 + quad * 4 + r;
        U[(size_t)row * NT + nt * 16 + n16] = acc[ms][nt][r];
      }
}

// ---------------------------------------------------------------------------
// Recurrent scan v3 (unchanged). 512 blocks x 256 threads, one batch row per
// block, G in registers, one LDS-only barrier per step, U prefetch 1 ahead.
// ---------------------------------------------------------------------------
__global__ __launch_bounds__(256, 2) void recur_kernel(
    const float* __restrict__ ws,
    const float* __restrict__ be, const float* __restrict__ bi,
    float* __restrict__ out) {
  __shared__ float rbuf[2][NT];       // [parity][j]
  __shared__ float balbuf[2][NT];
  __shared__ float biasL[NT];

  const int tid  = threadIdx.x;
  const int lane = tid & 63;
  const int wave = tid >> 6;
  const int jc   = (wave << 3) | (lane & 7);  // 0..31
  const int kc   = (lane >> 3) & 7;           // 0..7
  const int j0   = jc * 5;
  const int k0   = kc * 20;
  const int b    = blockIdx.x;

  const float* G = ws + G_OFF;
  const float* U = ws + U_OFF;

  float g[20][5];
  #pragma unroll
  for (int kk = 0; kk < 20; ++kk)
    #pragma unroll
    for (int c = 0; c < 5; ++c)
      g[kk][c] = G[(size_t)(k0 + kk) * NT + j0 + c];

  if (tid < NT) biasL[tid] = (tid < NE) ? be[tid] : bi[tid - NE];
  for (int i = tid; i < 2 * NT; i += 256) (&rbuf[0][0])[i] = 0.f;

  const bool owner = (kc == 0);
  float u[5];
  if (owner) {
    const size_t ub = ((size_t)b * LL) * NT + j0;
    #pragma unroll
    for (int c = 0; c < 5; ++c) u[c] = U[ub + c];
  }
  float s[5];
  #pragma unroll
  for (int c = 0; c < 5; ++c) s[c] = 0.f;

  __syncthreads();

  for (int l = 0; l < LL; ++l) {
    const int p = l & 1;
    // ---- store step l-1 outputs (no barrier depends on these) ----
    if (l > 0) {
      const size_t ob = (size_t)b * LL + (l - 1);
      if (tid < NE) {
        out[O_RE   + ob * NE + tid] = rbuf[p][tid];
        out[O_BALE + ob * NE + tid] = balbuf[p][tid];
      } else if (tid < NT) {
        const int j2 = tid - NE;
        out[O_RI   + ob * NI + j2] = rbuf[p][NE + j2];
        out[O_BALI + ob * NI + j2] = balbuf[p][NE + j2];
      }
    }
    // ---- prefetch next step's U (owners) ----
    float nu[5];
    if (owner && l + 1 < LL) {
      const size_t nb = ((size_t)b * LL + (l + 1)) * NT + j0;
      #pragma unroll
      for (int c = 0; c < 5; ++c) nu[c] = U[nb + c];
    }
    // ---- partial dots over this thread's k-chunk ----
    float a[5];
    #pragma unroll
    for (int c = 0; c < 5; ++c) a[c] = 0.f;
    #pragma unroll
    for (int kk4 = 0; kk4 < 5; ++kk4) {
      float4 rv = *(const float4*)(&rbuf[p][k0 + kk4 * 4]);
      #pragma unroll
      for (int c = 0; c < 5; ++c)
        a[c] += rv.x * g[kk4*4+0][c] + rv.y * g[kk4*4+1][c]
              + rv.z * g[kk4*4+2][c] + rv.w * g[kk4*4+3][c];
    }
    // ---- butterfly reduce over kc (lane bits 3..5) ----
    #pragma unroll
    for (int c = 0; c < 5; ++c) {
      float v = a[c];
      v += __shfl_xor(v, 8, 64);
      v += __shfl_xor(v, 16, 64);
      v += __shfl_xor(v, 32, 64);
      a[c] = v;
    }
    // ---- owner lanes update state, write next-parity buffers ----
    if (owner) {
      #pragma unroll
      for (int c = 0; c < 5; ++c) {
        float bal = a[c] + u[c];
        balbuf[1 - p][j0 + c] = bal;
        float sn = 0.5f * (s[c] + bal + biasL[j0 + c]);
        s[c] = sn;
        rbuf[1 - p][j0 + c] = fmaxf(sn, 0.f);
      }
      #pragma unroll
      for (int c = 0; c < 5; ++c) u[c] = nu[c];
    }
    LDS_BARRIER();
  }
  // ---- final store: step 63 outputs live in parity-0 buffers ----
  {
    const size_t ob = (size_t)b * LL + 63;
    if (tid < NE) {
      out[O_RE   + ob * NE + tid] = rbuf[0][tid];
      out[O_BALE + ob * NE + tid] = balbuf[0][tid];
    } else if (tid < NT) {
      const int j2 = tid - NE;
      out[O_RI   + ob * NI + j2] = rbuf[0][NE + j2];
      out[O_BALI + ob * NI + j2] = balbuf[0][NE + j2];
    }
  }
}

// ---------------------------------------------------------------------------
// Logits: [32768 x 128] @ Wro^T + bro. One thread per (m, class).
// ---------------------------------------------------------------------------
__global__ __launch_bounds__(256) void logits_kernel(const float* __restrict__ Wro,
                                                     const float* __restrict__ bro,
                                                     float* __restrict__ out) {
  __shared__ float WroL[NC * 132];   // row-stride 132 breaks bank alignment
  __shared__ float broL[NC];
  const int tid = threadIdx.x;
  for (int i = tid; i < NC * NE; i += 256) {
    int c = i >> 7, k = i & 127;
    WroL[c * 132 + k] = Wro[i];
  }
  if (tid < NC) broL[tid] = bro[tid];
  __syncthreads();
  const int idx = blockIdx.x * 256 + tid;   // 0..327679 exact
  const int m = idx / 10, c = idx - m * 10;
  const float* re = out + O_RE + (size_t)m * NE;
  float v = broL[c];
  #pragma unroll
  for (int t4 = 0; t4 < 32; ++t4) {
    float4 rv = *(const float4*)(re + t4 * 4);
    float4 wv = *(const float4*)(&WroL[c * 132 + t4 * 4]);
    v += rv.x * wv.x + rv.y * wv.y + rv.z * wv.z + rv.w * wv.w;
  }
  out[O_LOGITS + (size_t)m * NC + c] = v;
  if ((m & 63) == 63) out[O_LAST + (size_t)(m >> 6) * NC + c] = v;
}

extern "C" void kernel_launch(void* const* d_in, const int* in_sizes, int n_in,
                              void* d_out, int out_size, void* d_ws, size_t ws_size,
                              hipStream_t stream) {
  const float* x   = (const float*)d_in[0];
  const float* Wxe = (const float*)d_in[1];
  const float* Wxi = (const float*)d_in[2];
  const float* Wee = (const float*)d_in[3];
  const float* Wie = (const float*)d_in[4];
  const float* Wei = (const float*)d_in[5];
  const float* Wii = (const float*)d_in[6];
  const float* be  = (const float*)d_in[7];
  const float* bi  = (const float*)d_in[8];
  const float* Wro = (const float*)d_in[9];
  const float* bro = (const float*)d_in[10];
  float* ws  = (float*)d_ws;
  float* out = (float*)d_out;

  hipLaunchKernelGGL(prep_kernel, dim3((G_SZ + NT*KP + 255)/256), dim3(256), 0, stream,
                     Wxe, Wxi, Wee, Wie, Wei, Wii, ws);
  hipLaunchKernelGGL(gemm_kernel, dim3(MM/128), dim3(256), 0, stream,
                     x, ws, ws + U_OFF);
  hipLaunchKernelGGL(recur_kernel, dim3(BB), dim3(256), 0, stream,
                     ws, be, bi, out);
  hipLaunchKernelGGL(logits_kernel, dim3(MM * NC / 256), dim3(256), 0, stream,
                     Wro, bro, out);
}